// Round 7
// baseline (134.819 us; speedup 1.0000x reference)
//
#include <hip/hip_runtime.h>

// DifferentiableRGBtoVel: image (4,3,512,512) fp32, cmap (256,3) fp32, v_i (256) fp32
// out velocities (4,512,512) fp32.
//
// logit_k = -dist_k^2/(T*ln2) = A_k·p + B_k + C_p (exp2 form), A_k=2*K2*c_k,
// B_k=-K2*|c_k|^2, C_p=-K2*|p|^2, K2=1/(0.01*ln2)=144.27. All logits <= 0;
// C_p cancels in the softmax ratio (it only keeps exp2 in range).
//
// v7: model from R1-R6: the two quarter-rate v_exp_f32 serialize ~32 of v4's
// 57 cyc/pair on the VALU issue port; LLVM forms v_pk_*_f32 for pure
// <2 x float> chains but every scalar ESCAPE (v5 libcall, v6 inline asm)
// costs unpack/repack moves. So: poly exp2 in pure SSA, no asm, no libcall:
//   xc = pk_max(a, -120)            (weights < 2^-120 irrelevant; keeps the
//                                    exponent construct in normal range)
//   nf = rintf(xc) per element      (v_rndne_f32 on subregs; intrinsic ->
//                                    no register-pair breakup)
//   r  = xc - nf in [-0.5,0.5];  p = c0+c1 r+c2 r^2+c3 r^3  (pk fma chain)
//   w  = p * uint_as_float((n+127)<<23)   == ldexp(p, n), verified in v5/v6,
//        but 1 v_cvt_i32_f32 + 1 v_lshl_add_u32 per cell instead of libcall.
// Budget: ~36 cyc/pair vs v4's 57. 2 cells/lane keeps 2048 blocks =
// 8 waves/SIMD (v6's 4-cell variant starved occupancy: 4 waves/SIMD, 28%).

typedef float v2f __attribute__((ext_vector_type(2)));

#define HWSZ 262144              // 512*512
#define NPIX 1048576             // 4*512*512
#define K2F  144.2695040888963f  // 1/(0.01*ln2)

__global__ __launch_bounds__(256) void rgb2vel_prep(
    const float* __restrict__ cmap, const float* __restrict__ v_i,
    float4* __restrict__ ab, float* __restrict__ vv) {
  int k = threadIdx.x;  // 256 threads, 1 block
  float cx = cmap[k * 3 + 0];
  float cy = cmap[k * 3 + 1];
  float cz = cmap[k * 3 + 2];
  float4 r;
  r.x = 2.0f * K2F * cx;
  r.y = 2.0f * K2F * cy;
  r.z = 2.0f * K2F * cz;
  r.w = -K2F * (cx * cx + cy * cy + cz * cz);
  ab[k] = r;
  vv[k] = v_i[k];
}

__global__ __launch_bounds__(256) void rgb2vel_main(
    const float* __restrict__ img, const float4* __restrict__ ab,
    const float* __restrict__ vv, float* __restrict__ out) {
  int t = blockIdx.x * 256 + threadIdx.x;  // pair index, [0, NPIX/2)
  int n = t >> 17;                         // image index (131072 pairs/image)
  int hw2 = (t & 131071) << 1;             // first pixel of the pair
  const float* base = img + (size_t)n * 3 * HWSZ + hw2;
  v2f px = {base[0], base[1]};
  v2f py = {base[HWSZ], base[HWSZ + 1]};
  v2f pz = {base[2 * HWSZ], base[2 * HWSZ + 1]};

  // cp = -K2*|p|^2 per pixel (packed)
  v2f mk2 = {-K2F, -K2F};
  v2f cp = __builtin_elementwise_fma(
               px, px, __builtin_elementwise_fma(py, py, pz * pz)) *
           mk2;

  const v2f NEG120 = {-120.0f, -120.0f};
  const v2f C3 = {0.0555041f, 0.0555041f};
  const v2f C2 = {0.2426310f, 0.2426310f};
  const v2f C1 = {0.6931472f, 0.6931472f};
  const v2f C0 = {0.9999249f, 0.9999249f};

  v2f s = {0.0f, 0.0f};
  v2f sv = {0.0f, 0.0f};
#pragma unroll 16
  for (int k = 0; k < 256; ++k) {
    float4 c = ab[k];  // uniform index -> s_load_dwordx4
    v2f cx = {c.x, c.x};
    v2f cy = {c.y, c.y};
    v2f cz = {c.z, c.z};
    v2f cw = {c.w, c.w};
    // logit = A·p + B + cp   (1 pk add + 3 pk fma); always <= 0
    v2f a = __builtin_elementwise_fma(
        cx, px,
        __builtin_elementwise_fma(cy, py,
                                  __builtin_elementwise_fma(cz, pz, cw + cp)));
    // clamp so the exponent construct below stays in normal-float range
    v2f xc = __builtin_elementwise_max(a, NEG120);  // v_pk_max_f32
    // split: n = rint(xc) (v_rndne_f32 per subreg), r = xc - n in [-0.5,0.5]
    v2f nf;
    nf.x = __builtin_rintf(xc.x);
    nf.y = __builtin_rintf(xc.y);
    v2f r = xc - nf;
    // 2^r polynomial (3 pk fma, minimax rel err ~1.2e-4)
    v2f p = __builtin_elementwise_fma(
        __builtin_elementwise_fma(__builtin_elementwise_fma(C3, r, C2), r, C1),
        r, C0);
    // 2^n = uint_as_float((n+127)<<23): v_cvt_i32_f32 + v_lshl_add_u32 per
    // cell; exact for n in [-120, 0]. Identical value to v5/v6's ldexp.
    int n0 = (int)nf.x;
    int n1 = (int)nf.y;
    v2f sc;
    sc.x = __uint_as_float(((unsigned)(n0 + 127)) << 23);
    sc.y = __uint_as_float(((unsigned)(n1 + 127)) << 23);
    v2f w = p * sc;  // v_pk_mul_f32
    s = s + w;
    float vk = vv[k];  // uniform -> s_load
    v2f vkv = {vk, vk};
    sv = __builtin_elementwise_fma(w, vkv, sv);
  }
  float o0 = sv.x / s.x;
  float o1 = sv.y / s.y;
  size_t o = (size_t)2 * t;
  out[o] = o0;
  out[o + 1] = o1;
}

extern "C" void kernel_launch(void* const* d_in, const int* in_sizes, int n_in,
                              void* d_out, int out_size, void* d_ws, size_t ws_size,
                              hipStream_t stream) {
  const float* image = (const float*)d_in[0];  // (4,3,512,512)
  const float* cmap  = (const float*)d_in[1];  // (256,3)
  const float* v_i   = (const float*)d_in[2];  // (256,)
  float* out = (float*)d_out;                  // (4,512,512)

  float4* ab = (float4*)d_ws;                      // 256 * 16 B
  float*  vv = (float*)((char*)d_ws + 256 * 16);   // 256 * 4 B

  rgb2vel_prep<<<1, 256, 0, stream>>>(cmap, v_i, ab, vv);
  rgb2vel_main<<<NPIX / 2 / 256, 256, 0, stream>>>(image, ab, vv, out);
}

// Round 8
// 117.391 us; speedup vs baseline: 1.1485x; 1.1485x over previous
//
#include <hip/hip_runtime.h>

// DifferentiableRGBtoVel: image (4,3,512,512) fp32, cmap (256,3) fp32, v_i (256) fp32
// out velocities (4,512,512) fp32.
//
// logit_k = -dist_k^2/(T*ln2) = A_k·p + B_k + C_p (exp2 form), A_k=2*K2*c_k,
// B_k=-K2*|c_k|^2, C_p=-K2*|p|^2, K2=1/(0.01*ln2)=144.27. All logits <= 0;
// C_p cancels in the softmax ratio (it only keeps exp2 in range).
//
// v8: empirical model from R1-R7 — per-k-iter cost = overhead(~23cyc) +
// 2cyc/VALU-inst + ~7cyc/exp (trans pipe overlaps across waves). Poly-exp2
// paths are mathematically dead: their 8-10 extra insts (16-20 cyc) cost more
// than the hw exp's ~7. The biggest term is the per-iteration overhead, so:
// v4's verified scalar structure (plain floats, hw exp2, SGPR table loads)
// widened to 4 pixels/lane to amortize overhead over 2x the cells.
// Per-4-cell iter: 23 + 16 fma*2 + 4 exp*7 + 8 acc*2 = 99 cyc -> 24.8/cell
// (v4: 28.5). No ext_vector, no asm, no poly.

#define HWSZ 262144              // 512*512
#define NPIX 1048576             // 4*512*512
#define K2F  144.2695040888963f  // 1/(0.01*ln2)

__global__ __launch_bounds__(256) void rgb2vel_prep(
    const float* __restrict__ cmap, const float* __restrict__ v_i,
    float4* __restrict__ ab, float* __restrict__ vv) {
  int k = threadIdx.x;  // 256 threads, 1 block
  float cx = cmap[k * 3 + 0];
  float cy = cmap[k * 3 + 1];
  float cz = cmap[k * 3 + 2];
  float4 r;
  r.x = 2.0f * K2F * cx;
  r.y = 2.0f * K2F * cy;
  r.z = 2.0f * K2F * cz;
  r.w = -K2F * (cx * cx + cy * cy + cz * cz);
  ab[k] = r;
  vv[k] = v_i[k];
}

__global__ __launch_bounds__(256) void rgb2vel_main(
    const float* __restrict__ img, const float4* __restrict__ ab,
    const float* __restrict__ vv, float* __restrict__ out) {
  int t = blockIdx.x * 256 + threadIdx.x;  // quad index, [0, NPIX/4)
  int n = t >> 16;                         // image index (65536 quads/image)
  int hw4 = (t & 65535) << 2;              // first pixel of the quad
  const float* base = img + (size_t)n * 3 * HWSZ + hw4;
  float px0 = base[0], px1 = base[1], px2 = base[2], px3 = base[3];
  float py0 = base[HWSZ], py1 = base[HWSZ + 1];
  float py2 = base[HWSZ + 2], py3 = base[HWSZ + 3];
  float pz0 = base[2 * HWSZ], pz1 = base[2 * HWSZ + 1];
  float pz2 = base[2 * HWSZ + 2], pz3 = base[2 * HWSZ + 3];

  // cp = -K2*|p|^2 per pixel
  float cp0 = -K2F * fmaf(px0, px0, fmaf(py0, py0, pz0 * pz0));
  float cp1 = -K2F * fmaf(px1, px1, fmaf(py1, py1, pz1 * pz1));
  float cp2 = -K2F * fmaf(px2, px2, fmaf(py2, py2, pz2 * pz2));
  float cp3 = -K2F * fmaf(px3, px3, fmaf(py3, py3, pz3 * pz3));

  float s0 = 0.0f, s1 = 0.0f, s2 = 0.0f, s3 = 0.0f;
  float sv0 = 0.0f, sv1 = 0.0f, sv2 = 0.0f, sv3 = 0.0f;
#pragma unroll 16
  for (int k = 0; k < 256; ++k) {
    float4 c = ab[k];  // uniform index -> s_load_dwordx4
    float vk = vv[k];  // uniform -> s_load
    // logit = Ax*px + Ay*py + Az*pz + (B + cp); always <= 0
    float a0 = fmaf(c.x, px0, fmaf(c.y, py0, fmaf(c.z, pz0, c.w + cp0)));
    float a1 = fmaf(c.x, px1, fmaf(c.y, py1, fmaf(c.z, pz1, c.w + cp1)));
    float a2 = fmaf(c.x, px2, fmaf(c.y, py2, fmaf(c.z, pz2, c.w + cp2)));
    float a3 = fmaf(c.x, px3, fmaf(c.y, py3, fmaf(c.z, pz3, c.w + cp3)));
    float w0 = __builtin_amdgcn_exp2f(a0);
    float w1 = __builtin_amdgcn_exp2f(a1);
    float w2 = __builtin_amdgcn_exp2f(a2);
    float w3 = __builtin_amdgcn_exp2f(a3);
    s0 += w0;
    s1 += w1;
    s2 += w2;
    s3 += w3;
    sv0 = fmaf(w0, vk, sv0);
    sv1 = fmaf(w1, vk, sv1);
    sv2 = fmaf(w2, vk, sv2);
    sv3 = fmaf(w3, vk, sv3);
  }
  size_t o = (size_t)4 * t;
  out[o + 0] = sv0 / s0;
  out[o + 1] = sv1 / s1;
  out[o + 2] = sv2 / s2;
  out[o + 3] = sv3 / s3;
}

extern "C" void kernel_launch(void* const* d_in, const int* in_sizes, int n_in,
                              void* d_out, int out_size, void* d_ws, size_t ws_size,
                              hipStream_t stream) {
  const float* image = (const float*)d_in[0];  // (4,3,512,512)
  const float* cmap  = (const float*)d_in[1];  // (256,3)
  const float* v_i   = (const float*)d_in[2];  // (256,)
  float* out = (float*)d_out;                  // (4,512,512)

  float4* ab = (float4*)d_ws;                      // 256 * 16 B
  float*  vv = (float*)((char*)d_ws + 256 * 16);   // 256 * 4 B

  rgb2vel_prep<<<1, 256, 0, stream>>>(cmap, v_i, ab, vv);
  rgb2vel_main<<<NPIX / 4 / 256, 256, 0, stream>>>(image, ab, vv, out);
}